// Round 6
// baseline (823.276 us; speedup 1.0000x reference)
//
#include <hip/hip_runtime.h>
#include <cmath>
#include <cstdint>

constexpr int T_STEPS = 512;
constexpr int BATCH   = 1024;
constexpr int DIM     = 128;
constexpr int LATENT  = 256;
constexpr int OUT_DIM = 64;
constexpr int ROWS    = 16;               // batch rows per block
constexpr int NKSUB   = 48;               // (256+128)/8 k-subtiles

typedef __attribute__((ext_vector_type(8))) short bf16x8;   // MFMA A/B frag
typedef __attribute__((ext_vector_type(4))) float f32x4;    // MFMA C/D frag

__device__ __forceinline__ uint32_t f2bf(float f) {
    uint32_t u = __builtin_bit_cast(uint32_t, f);
    return (u + 0x7FFFu + ((u >> 16) & 1u)) >> 16;
}
__device__ __forceinline__ float bf2f(uint32_t b) {
    return __builtin_bit_cast(float, b << 16);
}
__device__ __forceinline__ uint32_t pk2(float a, float b) {
    return f2bf(a) | (f2bf(b) << 16);
}
// tanh(v) = 1 - 2/(e^{2v}+1); native exp2+rcp; saturates correctly at +-inf.
__device__ __forceinline__ float fast_tanh(float v) {
    float e = __builtin_amdgcn_exp2f(v * 2.885390081777927f);   // e^{2v}
    return __builtin_fmaf(-2.0f, __builtin_amdgcn_rcpf(e + 1.0f), 1.0f);
}
__device__ __forceinline__ float fast_sigmoid(float v) {
    float e = __builtin_amdgcn_exp2f(v * -1.4426950408889634f); // e^{-v}
    return __builtin_amdgcn_rcpf(e + 1.0f);
}

// grid = 64 blocks x 16 batch rows; block = 256 threads = 4 waves (1/SIMD).
// Wave wv owns output cols [64wv, 64wv+64) as 4 col-tiles; each A-frag is
// read ONCE per k-subtile and reused for 4 MFMAs -> LDS A-traffic 48KB/step
// (vs 192KB at 16x1 in round 5, which was LDS-BW-bound at 2880 cy/step).
// B = 48 named bf16x8 frags (192 VGPRs) persistent; waves_per_eu(1) -> 512.
__global__ void
__attribute__((amdgpu_flat_work_group_size(256, 256), amdgpu_waves_per_eu(1)))
rnn_mfma_w4(const float* __restrict__ x,    // [512][1024][128]
            const float* __restrict__ h0,   // [1024][256]
            const float* __restrict__ Wi,   // [128][256]
            const float* __restrict__ bi,   // [256]
            const float* __restrict__ Wh,   // [256][256]
            const float* __restrict__ Wd,   // [256][64]
            const float* __restrict__ bd,   // [64]
            float* __restrict__ out)        // [1024][64]
{
    __shared__ uint16_t als[2][NKSUB * 128];  // [ksub][row16][8] u16, dbuf

    const int tid   = threadIdx.x;
    const int lane  = tid & 63;
    const int wv    = tid >> 6;              // 0..3
    const int b0    = blockIdx.x * ROWS;
    const int row16 = lane & 15;
    const int kgrp  = lane >> 4;             // 0..3
    const int colb  = (wv << 6) + row16;     // col of tile 0

#define LOADB(NAME, P)                                                      \
    bf16x8 NAME; {                                                          \
        const float* _p = (P);                                              \
        NAME[0] = (short)f2bf(_p[0]);                                       \
        NAME[1] = (short)f2bf(_p[1 * LATENT]);                              \
        NAME[2] = (short)f2bf(_p[2 * LATENT]);                              \
        NAME[3] = (short)f2bf(_p[3 * LATENT]);                              \
        NAME[4] = (short)f2bf(_p[4 * LATENT]);                              \
        NAME[5] = (short)f2bf(_p[5 * LATENT]);                              \
        NAME[6] = (short)f2bf(_p[6 * LATENT]);                              \
        NAME[7] = (short)f2bf(_p[7 * LATENT]);                              \
    }
#define BPH(KK, CT) (Wh + (size_t)((KK) * 32 + kgrp * 8) * LATENT + colb + ((CT) << 4))
#define BPX(KK, CT) (Wi + (size_t)(((KK) - 8) * 32 + kgrp * 8) * LATENT + colb + ((CT) << 4))
#define DECL4H(KK) LOADB(B##KK##_0, BPH(KK,0)) LOADB(B##KK##_1, BPH(KK,1)) \
                   LOADB(B##KK##_2, BPH(KK,2)) LOADB(B##KK##_3, BPH(KK,3))
#define DECL4X(KK) LOADB(B##KK##_0, BPX(KK,0)) LOADB(B##KK##_1, BPX(KK,1)) \
                   LOADB(B##KK##_2, BPX(KK,2)) LOADB(B##KK##_3, BPX(KK,3))
    DECL4H(0) DECL4H(1) DECL4H(2) DECL4H(3)
    DECL4H(4) DECL4H(5) DECL4H(6) DECL4H(7)
    DECL4X(8) DECL4X(9) DECL4X(10) DECL4X(11)

    const float cb0 = bi[colb];
    const float cb1 = bi[colb + 16];
    const float cb2 = bi[colb + 32];
    const float cb3 = bi[colb + 48];

    // ---- prologue: stage h0 and x(t=0) into als[0] ----
    const int pr = tid & 15;                 // batch row
    const int pq = tid >> 4;                 // 0..15
    {
        // h0: 16 cols per thread -> 2 k-subtiles
        const float* hrow = h0 + (size_t)(b0 + pr) * LATENT + (pq << 4);
        float4 a0 = reinterpret_cast<const float4*>(hrow)[0];
        float4 a1 = reinterpret_cast<const float4*>(hrow)[1];
        float4 a2 = reinterpret_cast<const float4*>(hrow)[2];
        float4 a3 = reinterpret_cast<const float4*>(hrow)[3];
        uint4* d0 = reinterpret_cast<uint4*>(&als[0][((pq * 2) * 16 + pr) * 8]);
        uint4* d1 = reinterpret_cast<uint4*>(&als[0][((pq * 2 + 1) * 16 + pr) * 8]);
        *d0 = make_uint4(pk2(a0.x, a0.y), pk2(a0.z, a0.w), pk2(a1.x, a1.y), pk2(a1.z, a1.w));
        *d1 = make_uint4(pk2(a2.x, a2.y), pk2(a2.z, a2.w), pk2(a3.x, a3.y), pk2(a3.z, a3.w));
        // x0: 8 dims per thread -> 1 k-subtile (32+pq)
        const float* xrow = x + (size_t)(b0 + pr) * DIM + (pq << 3);
        float4 b0v = reinterpret_cast<const float4*>(xrow)[0];
        float4 b1v = reinterpret_cast<const float4*>(xrow)[1];
        uint4* dx = reinterpret_cast<uint4*>(&als[0][((32 + pq) * 16 + pr) * 8]);
        *dx = make_uint4(pk2(b0v.x, b0v.y), pk2(b0v.z, b0v.w), pk2(b1v.x, b1v.y), pk2(b1v.z, b1v.w));
    }
    __syncthreads();

    const int aoff = kgrp * 128 + row16 * 8;     // A-frag base (u16 idx)
    // x prefetch pointer (t=1 position)
    const float* xp = x + ((size_t)BATCH + b0 + pr) * DIM + (pq << 3);
    const int xwb = ((32 + pq) * 16 + pr) * 8;   // x writeback base (u16 idx)

    int cur = 0;
    for (int t = 0; t < T_STEPS; ++t) {
        const bool pf = (t + 1 < T_STEPS);
        float4 xv0, xv1;
        if (pf) {
            xv0 = reinterpret_cast<const float4*>(xp)[0];
            xv1 = reinterpret_cast<const float4*>(xp)[1];
            xp += (size_t)BATCH * DIM;
        }

        f32x4 c0 = {cb0, cb0, cb0, cb0};
        f32x4 c1 = {cb1, cb1, cb1, cb1};
        f32x4 c2 = {cb2, cb2, cb2, cb2};
        f32x4 c3 = {cb3, cb3, cb3, cb3};
        const uint16_t* ab = &als[cur][aoff];
#define MSTEP(KK) {                                                         \
        const bf16x8 a = *reinterpret_cast<const bf16x8*>(ab + (KK) * 512); \
        c0 = __builtin_amdgcn_mfma_f32_16x16x32_bf16(a, B##KK##_0, c0, 0, 0, 0); \
        c1 = __builtin_amdgcn_mfma_f32_16x16x32_bf16(a, B##KK##_1, c1, 0, 0, 0); \
        c2 = __builtin_amdgcn_mfma_f32_16x16x32_bf16(a, B##KK##_2, c2, 0, 0, 0); \
        c3 = __builtin_amdgcn_mfma_f32_16x16x32_bf16(a, B##KK##_3, c3, 0, 0, 0); }
        MSTEP(0) MSTEP(1) MSTEP(2)  MSTEP(3)
        MSTEP(4) MSTEP(5) MSTEP(6)  MSTEP(7)
        MSTEP(8) MSTEP(9) MSTEP(10) MSTEP(11)

        const int nxt = cur ^ 1;
        // h_{t+1} = tanh(c) -> bf16 -> als[nxt]; wave writes its 64 cols
#define WB(CT, CV) {                                                        \
        const int col = colb + ((CT) << 4);                                 \
        uint16_t* hw = &als[nxt][(col >> 3) * 128 + (col & 7)];             \
        hw[(kgrp * 4 + 0) * 8] = (uint16_t)f2bf(fast_tanh(CV[0]));          \
        hw[(kgrp * 4 + 1) * 8] = (uint16_t)f2bf(fast_tanh(CV[1]));          \
        hw[(kgrp * 4 + 2) * 8] = (uint16_t)f2bf(fast_tanh(CV[2]));          \
        hw[(kgrp * 4 + 3) * 8] = (uint16_t)f2bf(fast_tanh(CV[3])); }
        WB(0, c0) WB(1, c1) WB(2, c2) WB(3, c3)

        // x_{t+1} -> als[nxt] x-region (one b128 store per thread)
        if (pf) {
            uint4* dx = reinterpret_cast<uint4*>(&als[nxt][xwb]);
            *dx = make_uint4(pk2(xv0.x, xv0.y), pk2(xv0.z, xv0.w),
                             pk2(xv1.x, xv1.y), pk2(xv1.z, xv1.w));
        }
        __syncthreads();
        cur = nxt;
    }

    // ---- decode: out = sigmoid(h_final @ Wd + bd), 4 rows per thread ----
    {
        const int o  = tid & 63;
        const int rb = tid >> 6;             // rows rb, rb+4, rb+8, rb+12
        float s0 = bd[o], s1 = s0, s2 = s0, s3 = s0;
        const uint16_t* hb = als[cur];
        #pragma unroll 8
        for (int k = 0; k < LATENT; k += 2) {
            const float w0 = Wd[(size_t)k * OUT_DIM + o];
            const float w1 = Wd[(size_t)(k + 1) * OUT_DIM + o];
            const int bx = (k >> 3) * 128 + (k & 7);
            uint32_t p;
            p = *reinterpret_cast<const uint32_t*>(&hb[bx + (rb     ) * 8]);
            s0 += bf2f(p & 0xFFFFu) * w0 + bf2f(p >> 16) * w1;
            p = *reinterpret_cast<const uint32_t*>(&hb[bx + (rb +  4) * 8]);
            s1 += bf2f(p & 0xFFFFu) * w0 + bf2f(p >> 16) * w1;
            p = *reinterpret_cast<const uint32_t*>(&hb[bx + (rb +  8) * 8]);
            s2 += bf2f(p & 0xFFFFu) * w0 + bf2f(p >> 16) * w1;
            p = *reinterpret_cast<const uint32_t*>(&hb[bx + (rb + 12) * 8]);
            s3 += bf2f(p & 0xFFFFu) * w0 + bf2f(p >> 16) * w1;
        }
        out[(size_t)(b0 + rb     ) * OUT_DIM + o] = fast_sigmoid(s0);
        out[(size_t)(b0 + rb +  4) * OUT_DIM + o] = fast_sigmoid(s1);
        out[(size_t)(b0 + rb +  8) * OUT_DIM + o] = fast_sigmoid(s2);
        out[(size_t)(b0 + rb + 12) * OUT_DIM + o] = fast_sigmoid(s3);
    }
}

extern "C" void kernel_launch(void* const* d_in, const int* in_sizes, int n_in,
                              void* d_out, int out_size, void* d_ws, size_t ws_size,
                              hipStream_t stream) {
    const float* x  = (const float*)d_in[0];
    const float* h0 = (const float*)d_in[1];
    const float* Wi = (const float*)d_in[2];
    const float* bi = (const float*)d_in[3];
    const float* Wh = (const float*)d_in[4];
    const float* Wd = (const float*)d_in[5];
    const float* bd = (const float*)d_in[6];
    float* out = (float*)d_out;

    hipLaunchKernelGGL(rnn_mfma_w4, dim3(BATCH / ROWS), dim3(256), 0, stream,
                       x, h0, Wi, bi, Wh, Wd, bd, out);
}

// Round 7
// 438.665 us; speedup vs baseline: 1.8768x; 1.8768x over previous
//
#include <hip/hip_runtime.h>
#include <cmath>
#include <cstdint>

constexpr int T_STEPS = 512;
constexpr int BATCH   = 1024;
constexpr int DIM     = 128;
constexpr int LATENT  = 256;
constexpr int OUT_DIM = 64;
constexpr int ROWS    = 16;               // batch rows per block
constexpr int NKSUB   = 48;               // (256+128)/8 k-subtiles

typedef __attribute__((ext_vector_type(8))) short bf16x8;   // MFMA A/B frag
typedef __attribute__((ext_vector_type(4))) float f32x4;    // MFMA C/D frag

__device__ __forceinline__ uint32_t f2bf(float f) {
    uint32_t u = __builtin_bit_cast(uint32_t, f);
    return (u + 0x7FFFu + ((u >> 16) & 1u)) >> 16;
}
__device__ __forceinline__ float bf2f(uint32_t b) {
    return __builtin_bit_cast(float, b << 16);
}
__device__ __forceinline__ uint32_t pk2(float a, float b) {
    return f2bf(a) | (f2bf(b) << 16);
}
// tanh(v) = 1 - 2/(e^{2v}+1); native exp2+rcp; saturates correctly at +-inf.
__device__ __forceinline__ float fast_tanh(float v) {
    float e = __builtin_amdgcn_exp2f(v * 2.885390081777927f);   // e^{2v}
    return __builtin_fmaf(-2.0f, __builtin_amdgcn_rcpf(e + 1.0f), 1.0f);
}
__device__ __forceinline__ float fast_sigmoid(float v) {
    float e = __builtin_amdgcn_exp2f(v * -1.4426950408889634f); // e^{-v}
    return __builtin_amdgcn_rcpf(e + 1.0f);
}

// grid = 64 blocks x 16 batch rows; block = 512 threads = 8 waves (2/SIMD).
// Wave wv owns cols [32wv, 32wv+32) = 2 col-tiles: each A-frag ds_read is
// reused for 2 MFMAs -> A-traffic 96KB/step/CU (r5: 192KB, LDS-BW-bound),
// while keeping 2 waves/SIMD latency hiding (r6 had 1/SIMD -> stalled).
// B = 24 named bf16x8 frags = 96 regs -> fits the DEFAULT 128-AGPR budget
// (r6's 192 overflowed to scratch; the waves_per_eu/launch_bounds knobs
// demonstrably do not raise the cap).
__global__ __launch_bounds__(512)
void rnn_mfma_w8t2(const float* __restrict__ x,    // [512][1024][128]
                   const float* __restrict__ h0,   // [1024][256]
                   const float* __restrict__ Wi,   // [128][256]
                   const float* __restrict__ bi,   // [256]
                   const float* __restrict__ Wh,   // [256][256]
                   const float* __restrict__ Wd,   // [256][64]
                   const float* __restrict__ bd,   // [64]
                   float* __restrict__ out)        // [1024][64]
{
    __shared__ uint16_t als[2][NKSUB * 128];  // [ksub][row16][8] u16, dbuf

    const int tid   = threadIdx.x;
    const int lane  = tid & 63;
    const int wv    = tid >> 6;              // 0..7
    const int b0    = blockIdx.x * ROWS;
    const int row16 = lane & 15;
    const int kgrp  = lane >> 4;             // 0..3
    const int col0  = (wv << 5) + row16;     // col of tile 0 (tile1 = +16)

#define LOADB(NAME, P)                                                      \
    bf16x8 NAME; {                                                          \
        const float* _p = (P);                                              \
        NAME[0] = (short)f2bf(_p[0]);                                       \
        NAME[1] = (short)f2bf(_p[1 * LATENT]);                              \
        NAME[2] = (short)f2bf(_p[2 * LATENT]);                              \
        NAME[3] = (short)f2bf(_p[3 * LATENT]);                              \
        NAME[4] = (short)f2bf(_p[4 * LATENT]);                              \
        NAME[5] = (short)f2bf(_p[5 * LATENT]);                              \
        NAME[6] = (short)f2bf(_p[6 * LATENT]);                              \
        NAME[7] = (short)f2bf(_p[7 * LATENT]);                              \
    }
#define BPH(KK, CT) (Wh + (size_t)((KK) * 32 + kgrp * 8) * LATENT + col0 + ((CT) << 4))
#define BPX(KK, CT) (Wi + (size_t)(((KK) - 8) * 32 + kgrp * 8) * LATENT + col0 + ((CT) << 4))
#define DECL2H(KK) LOADB(B##KK##_0, BPH(KK,0)) LOADB(B##KK##_1, BPH(KK,1))
#define DECL2X(KK) LOADB(B##KK##_0, BPX(KK,0)) LOADB(B##KK##_1, BPX(KK,1))
    DECL2H(0) DECL2H(1) DECL2H(2)  DECL2H(3)
    DECL2H(4) DECL2H(5) DECL2H(6)  DECL2H(7)
    DECL2X(8) DECL2X(9) DECL2X(10) DECL2X(11)

    const float cb0 = bi[col0];
    const float cb1 = bi[col0 + 16];

    // ---- prologue: stage h0 and x(t=0) into als[0] ----
    const int pr = tid & 15;                 // batch row
    const int pq = tid >> 4;                 // 0..31
    {
        // h0: 8 cols per thread -> one uint4 into k-subtile pq
        const float* hrow = h0 + (size_t)(b0 + pr) * LATENT + (pq << 3);
        float4 a0 = reinterpret_cast<const float4*>(hrow)[0];
        float4 a1 = reinterpret_cast<const float4*>(hrow)[1];
        *reinterpret_cast<uint4*>(&als[0][(pq * 16 + pr) * 8]) =
            make_uint4(pk2(a0.x, a0.y), pk2(a0.z, a0.w),
                       pk2(a1.x, a1.y), pk2(a1.z, a1.w));
        // x0: 4 dims per thread -> one uint2 into k-subtile 32+(pq>>1)
        const float* xrow = x + (size_t)(b0 + pr) * DIM + (pq << 2);
        float4 xv = *reinterpret_cast<const float4*>(xrow);
        uint2* dx = reinterpret_cast<uint2*>(
            &als[0][((32 + (pq >> 1)) * 16 + pr) * 8 + ((pq & 1) << 2)]);
        *dx = make_uint2(pk2(xv.x, xv.y), pk2(xv.z, xv.w));
    }
    __syncthreads();

    const int aoff = kgrp * 128 + row16 * 8;     // A-frag base (u16 idx)
    const float* xp = x + ((size_t)BATCH + b0 + pr) * DIM + (pq << 2);  // t=1
    const int xwb = ((32 + (pq >> 1)) * 16 + pr) * 8 + ((pq & 1) << 2);

    int cur = 0;
    for (int t = 0; t < T_STEPS; ++t) {
        const bool pf = (t + 1 < T_STEPS);
        float4 xv;
        if (pf) {
            xv = *reinterpret_cast<const float4*>(xp);
            xp += (size_t)BATCH * DIM;
        }

        f32x4 c0 = {cb0, cb0, cb0, cb0};
        f32x4 c1 = {cb1, cb1, cb1, cb1};
        const uint16_t* ab = &als[cur][aoff];
#define MSTEP(KK) {                                                         \
        const bf16x8 a = *reinterpret_cast<const bf16x8*>(ab + (KK) * 512); \
        c0 = __builtin_amdgcn_mfma_f32_16x16x32_bf16(a, B##KK##_0, c0, 0, 0, 0); \
        c1 = __builtin_amdgcn_mfma_f32_16x16x32_bf16(a, B##KK##_1, c1, 0, 0, 0); }
        MSTEP(0) MSTEP(1) MSTEP(2)  MSTEP(3)
        MSTEP(4) MSTEP(5) MSTEP(6)  MSTEP(7)
        MSTEP(8) MSTEP(9) MSTEP(10) MSTEP(11)

        const int nxt = cur ^ 1;
        // h_{t+1} = tanh(c) -> bf16 -> als[nxt]; wave writes its 32 cols
#define WB(CT, CV) {                                                        \
        const int col = col0 + ((CT) << 4);                                 \
        uint16_t* hw = &als[nxt][(col >> 3) * 128 + (col & 7)];             \
        hw[(kgrp * 4 + 0) * 8] = (uint16_t)f2bf(fast_tanh(CV[0]));          \
        hw[(kgrp * 4 + 1) * 8] = (uint16_t)f2bf(fast_tanh(CV[1]));          \
        hw[(kgrp * 4 + 2) * 8] = (uint16_t)f2bf(fast_tanh(CV[2]));          \
        hw[(kgrp * 4 + 3) * 8] = (uint16_t)f2bf(fast_tanh(CV[3])); }
        WB(0, c0) WB(1, c1)

        // x_{t+1} -> als[nxt] x-region (one uint2 store per thread)
        if (pf)
            *reinterpret_cast<uint2*>(&als[nxt][xwb]) =
                make_uint2(pk2(xv.x, xv.y), pk2(xv.z, xv.w));

        __syncthreads();
        cur = nxt;
    }

    // ---- decode: out = sigmoid(h_final @ Wd + bd), 2 rows per thread ----
    {
        const int o  = tid & 63;
        const int rb = tid >> 6;             // rows rb, rb+8
        float s0 = bd[o], s1 = s0;
        const uint16_t* hb = als[cur];
        #pragma unroll 8
        for (int k = 0; k < LATENT; k += 2) {
            const float w0 = Wd[(size_t)k * OUT_DIM + o];
            const float w1 = Wd[(size_t)(k + 1) * OUT_DIM + o];
            const int bx = (k >> 3) * 128 + (k & 7);
            uint32_t p;
            p = *reinterpret_cast<const uint32_t*>(&hb[bx + rb * 8]);
            s0 += bf2f(p & 0xFFFFu) * w0 + bf2f(p >> 16) * w1;
            p = *reinterpret_cast<const uint32_t*>(&hb[bx + (rb + 8) * 8]);
            s1 += bf2f(p & 0xFFFFu) * w0 + bf2f(p >> 16) * w1;
        }
        out[(size_t)(b0 + rb    ) * OUT_DIM + o] = fast_sigmoid(s0);
        out[(size_t)(b0 + rb + 8) * OUT_DIM + o] = fast_sigmoid(s1);
    }
}

extern "C" void kernel_launch(void* const* d_in, const int* in_sizes, int n_in,
                              void* d_out, int out_size, void* d_ws, size_t ws_size,
                              hipStream_t stream) {
    const float* x  = (const float*)d_in[0];
    const float* h0 = (const float*)d_in[1];
    const float* Wi = (const float*)d_in[2];
    const float* bi = (const float*)d_in[3];
    const float* Wh = (const float*)d_in[4];
    const float* Wd = (const float*)d_in[5];
    const float* bd = (const float*)d_in[6];
    float* out = (float*)d_out;

    hipLaunchKernelGGL(rnn_mfma_w8t2, dim3(BATCH / ROWS), dim3(512), 0, stream,
                       x, h0, Wi, bi, Wh, Wd, bd, out);
}